// Round 15
// baseline (347.965 us; speedup 1.0000x reference)
//
#include <hip/hip_runtime.h>
#include <hip/hip_bf16.h>

// GCN encoder: 2x GCNConv(relu) + global mean pool.
// N=100000 nodes, E=1.6M edges, D 128->128->64, G=64 graphs.
// Round 15: r14 reverted (bf16 LDS pack cost VALU, occupancy unchanged).
// Fusion re-paired: deg_count runs STANDALONE (regains full TLP); gemm1 is
// instead interleaved with the atomic-free scatter (both ~35us, independent,
// different pipes). Fat kernel = r13's f32 32KB gemm tile + scatter role.

#define DIN 128
#define DH  128
#define DOUTC 64

// bf16 helpers (RNE pack, shift unpack)
__device__ inline unsigned short f2bf(float f) {
    union { float f; unsigned u; } v; v.f = f;
    unsigned r = v.u + 0x7FFF + ((v.u >> 16) & 1);
    return (unsigned short)(r >> 16);
}
__device__ inline float bf_lo(unsigned u) { return __uint_as_float(u << 16); }
__device__ inline float bf_hi(unsigned u) { return __uint_as_float(u & 0xFFFF0000u); }

// ---------------- init: zero deg + zero pool sums in one launch ----------------
__global__ void init_kernel(int* __restrict__ deg, float* __restrict__ sums, int n, int m) {
    int i = blockIdx.x * blockDim.x + threadIdx.x;
    if (i < n) deg[i] = 0;
    if (i < m) sums[i] = 0.0f;
}

// count in-degrees AND record each edge's rank within its dst segment
__global__ void deg_count_kernel(int* __restrict__ cnt, const int* __restrict__ dst,
                                 int* __restrict__ rank, int e) {
    int i = blockIdx.x * blockDim.x + threadIdx.x;
    if (i < e) rank[i] = atomicAdd(&cnt[dst[i]], 1);
}

// ---------------- prefix scan over deg -> row_ptr; also emits dinv ----------
__global__ __launch_bounds__(256) void scan1_kernel(const int* __restrict__ deg,
                                                    int* __restrict__ excl,
                                                    int* __restrict__ blockSums,
                                                    float* __restrict__ dinv, int n) {
    __shared__ int sh[256];
    const int tid = threadIdx.x;
    const int base = blockIdx.x * 1024 + tid * 4;
    int v[4];
    #pragma unroll
    for (int j = 0; j < 4; ++j) v[j] = (base + j < n) ? deg[base + j] : 0;
    #pragma unroll
    for (int j = 0; j < 4; ++j)
        if (base + j < n) dinv[base + j] = rsqrtf((float)(v[j] + 1));
    int tsum = v[0] + v[1] + v[2] + v[3];
    sh[tid] = tsum;
    __syncthreads();
    for (int off = 1; off < 256; off <<= 1) {
        int add = (tid >= off) ? sh[tid - off] : 0;
        __syncthreads();
        sh[tid] += add;
        __syncthreads();
    }
    int texcl = sh[tid] - tsum;
    int run = texcl;
    #pragma unroll
    for (int j = 0; j < 4; ++j) {
        if (base + j < n) excl[base + j] = run;
        run += v[j];
    }
    if (tid == 255) blockSums[blockIdx.x] = sh[255];
}

__global__ void scan2_kernel(int* __restrict__ blockSums, int nb) {
    if (blockIdx.x == 0 && threadIdx.x == 0) {
        int run = 0;
        for (int i = 0; i < nb; ++i) {
            int t = blockSums[i];
            blockSums[i] = run;
            run += t;
        }
    }
}

__global__ void scan3_kernel(int* __restrict__ row_ptr, const int* __restrict__ blockSums,
                             int n, int e_total) {
    int i = blockIdx.x * blockDim.x + threadIdx.x;
    if (i < n) row_ptr[i] += blockSums[i >> 10];
    if (i == 0) row_ptr[n] = e_total;
}

// ---------------- fat kernel: interleaved gemm1 / scatter blocks ----------------
// role: bid%5==0 && bid/5<nG -> gemm block (64 rows, f32 32KB LDS);
// else scatter block: ep[row_ptr[dst]+rank[e]] = {src, dinv[src]*dinv[dst]}.
__global__ __launch_bounds__(256) void gemm1_scatter_kernel(const float* __restrict__ X,
                                                            const float* __restrict__ W,
                                                            unsigned short* __restrict__ Y, int n,
                                                            const int* __restrict__ src,
                                                            const int* __restrict__ dst,
                                                            const int* __restrict__ rank,
                                                            const float* __restrict__ dinv,
                                                            const int* __restrict__ row_ptr,
                                                            int2* __restrict__ ep,
                                                            int e_total, int nG) {
    __shared__ float xs[64][128];   // 32 KB (gemm role only)
    const int tid = threadIdx.x;
    const int bid = (int)blockIdx.x;
    const int q = bid / 5;
    const int r5 = bid % 5;
    const bool isGemm = (r5 == 0) && (q < nG);

    if (!isGemm) {
        int gBefore = (r5 == 0) ? q : q + 1;
        if (gBefore > nG) gBefore = nG;
        int sBlk = bid - gBefore;
        int e = sBlk * 256 + tid;
        if (e < e_total) {
            int s = src[e];
            int d = dst[e];
            int r = rank[e];
            float ds = dinv[s];
            float dd = dinv[d];
            int pos = row_ptr[d] + r;
            ep[pos] = make_int2(s, __float_as_int(ds * dd));
        }
        return;
    }

    constexpr int COLV = 32;   // 128/4 float4 col groups
    constexpr int RS = 8;      // 256/COLV row slots
    constexpr int RPT = 8;     // 64/RS rows per thread

    const int row0 = q * 64;

    #pragma unroll
    for (int i = 0; i < 8; ++i) {
        int idx = i * 256 + tid;
        int r = idx >> 5;
        int c = idx & 31;
        int gr = row0 + r;
        float4 v = make_float4(0.f, 0.f, 0.f, 0.f);
        if (gr < n) v = reinterpret_cast<const float4*>(X)[(size_t)gr * 32 + c];
        reinterpret_cast<float4*>(&xs[0][0])[idx] = v;
    }
    __syncthreads();

    const int col = tid % COLV;
    const int rslot = tid / COLV;

    float4 acc[RPT];
    #pragma unroll
    for (int r = 0; r < RPT; ++r) acc[r] = make_float4(0.f, 0.f, 0.f, 0.f);

    #pragma unroll 4
    for (int k = 0; k < 128; ++k) {
        float4 w = reinterpret_cast<const float4*>(W)[k * COLV + col];
        #pragma unroll
        for (int r = 0; r < RPT; ++r) {
            float xv = xs[rslot + r * RS][k];
            acc[r].x += xv * w.x;
            acc[r].y += xv * w.y;
            acc[r].z += xv * w.z;
            acc[r].w += xv * w.w;
        }
    }

    #pragma unroll
    for (int r = 0; r < RPT; ++r) {
        int gr = row0 + rslot + r * RS;
        if (gr < n) {
            ushort4 st;
            st.x = f2bf(acc[r].x);
            st.y = f2bf(acc[r].y);
            st.z = f2bf(acc[r].z);
            st.w = f2bf(acc[r].w);
            reinterpret_cast<ushort4*>(Y)[(size_t)gr * COLV + col] = st;
        }
    }
}

// ---------------- GEMM2: Y[n][DOUT] = H1[n][128](bf16) * W[128][DOUT], bf16 out ----
template <int DOUT>
__global__ __launch_bounds__(256) void gemm_k128_bf16in(const unsigned short* __restrict__ X,
                                                        const float* __restrict__ W,
                                                        unsigned short* __restrict__ Y, int n) {
    constexpr int COLV = DOUT / 4;
    constexpr int RS = 256 / COLV;
    constexpr int RPT = 64 / RS;

    __shared__ float xs[64][128];

    const int tid = threadIdx.x;
    const int row0 = (int)blockIdx.x * 64;

    // stage 64x128 bf16 tile -> f32 LDS: 1024 uint4 (16B = 8 bf16), 4/thread
    #pragma unroll
    for (int i = 0; i < 4; ++i) {
        int idx = i * 256 + tid;     // uint4 index; 16 per row
        int r = idx >> 4;
        int c8 = idx & 15;
        uint4 v = make_uint4(0, 0, 0, 0);
        if (row0 + r < n) v = reinterpret_cast<const uint4*>(X)[(size_t)(row0 + r) * 16 + c8];
        float* dp = &xs[r][c8 * 8];
        dp[0] = bf_lo(v.x); dp[1] = bf_hi(v.x);
        dp[2] = bf_lo(v.y); dp[3] = bf_hi(v.y);
        dp[4] = bf_lo(v.z); dp[5] = bf_hi(v.z);
        dp[6] = bf_lo(v.w); dp[7] = bf_hi(v.w);
    }
    __syncthreads();

    const int col = tid % COLV;
    const int rslot = tid / COLV;

    float4 acc[RPT];
    #pragma unroll
    for (int r = 0; r < RPT; ++r) acc[r] = make_float4(0.f, 0.f, 0.f, 0.f);

    #pragma unroll 4
    for (int k = 0; k < 128; ++k) {
        float4 w = reinterpret_cast<const float4*>(W)[k * COLV + col];
        #pragma unroll
        for (int r = 0; r < RPT; ++r) {
            float xv = xs[rslot + r * RS][k];
            acc[r].x += xv * w.x;
            acc[r].y += xv * w.y;
            acc[r].z += xv * w.z;
            acc[r].w += xv * w.w;
        }
    }

    #pragma unroll
    for (int r = 0; r < RPT; ++r) {
        int gr = row0 + rslot + r * RS;
        if (gr < n) {
            ushort4 st;
            st.x = f2bf(acc[r].x);
            st.y = f2bf(acc[r].y);
            st.z = f2bf(acc[r].z);
            st.w = f2bf(acc[r].w);
            reinterpret_cast<ushort4*>(Y)[(size_t)gr * COLV + col] = st;
        }
    }
}

// ---------------- fused CSR aggregation + selfloop + bias + relu ----------------
// One wave per node; 8x unrolled edge loop over int2 {src, norm} records;
// XW bf16, f32 accumulation. BFOUT selects bf16 vs f32 output.
template <int D, bool BFOUT>
__global__ __launch_bounds__(256) void agg_relu_kernel(const unsigned short* __restrict__ XW,
                                                       const int2* __restrict__ ep,
                                                       const int* __restrict__ row_ptr,
                                                       const float* __restrict__ dinv,
                                                       const float* __restrict__ bias,
                                                       void* __restrict__ OUT, int n) {
    const int tid = threadIdx.x;
    const int node = (blockIdx.x * 256 + tid) >> 6;
    const int lane = tid & 63;
    if (node >= n) return;

    const int start = row_ptr[node];
    const int end = row_ptr[node + 1];

    if constexpr (D == 128) {
        const unsigned* XWu = reinterpret_cast<const unsigned*>(XW);  // 64 uints/row
        float di = dinv[node];
        float sl = di * di;
        unsigned rv = XWu[(size_t)node * 64 + lane];
        float ax = bf_lo(rv) * sl, ay = bf_hi(rv) * sl;
        float bx = 0.f, by = 0.f;

        int p = start;
        for (; p + 8 <= end; p += 8) {
            int2 m0 = ep[p + 0]; int2 m1 = ep[p + 1];
            int2 m2 = ep[p + 2]; int2 m3 = ep[p + 3];
            int2 m4 = ep[p + 4]; int2 m5 = ep[p + 5];
            int2 m6 = ep[p + 6]; int2 m7 = ep[p + 7];
            unsigned u0 = XWu[(size_t)m0.x * 64 + lane];
            unsigned u1 = XWu[(size_t)m1.x * 64 + lane];
            unsigned u2 = XWu[(size_t)m2.x * 64 + lane];
            unsigned u3 = XWu[(size_t)m3.x * 64 + lane];
            unsigned u4 = XWu[(size_t)m4.x * 64 + lane];
            unsigned u5 = XWu[(size_t)m5.x * 64 + lane];
            unsigned u6 = XWu[(size_t)m6.x * 64 + lane];
            unsigned u7 = XWu[(size_t)m7.x * 64 + lane];
            float w0 = __int_as_float(m0.y), w1 = __int_as_float(m1.y);
            float w2 = __int_as_float(m2.y), w3 = __int_as_float(m3.y);
            float w4 = __int_as_float(m4.y), w5 = __int_as_float(m5.y);
            float w6 = __int_as_float(m6.y), w7 = __int_as_float(m7.y);
            ax += bf_lo(u0) * w0; ay += bf_hi(u0) * w0;
            bx += bf_lo(u1) * w1; by += bf_hi(u1) * w1;
            ax += bf_lo(u2) * w2; ay += bf_hi(u2) * w2;
            bx += bf_lo(u3) * w3; by += bf_hi(u3) * w3;
            ax += bf_lo(u4) * w4; ay += bf_hi(u4) * w4;
            bx += bf_lo(u5) * w5; by += bf_hi(u5) * w5;
            ax += bf_lo(u6) * w6; ay += bf_hi(u6) * w6;
            bx += bf_lo(u7) * w7; by += bf_hi(u7) * w7;
        }
        for (; p + 4 <= end; p += 4) {
            int2 m0 = ep[p + 0]; int2 m1 = ep[p + 1];
            int2 m2 = ep[p + 2]; int2 m3 = ep[p + 3];
            unsigned u0 = XWu[(size_t)m0.x * 64 + lane];
            unsigned u1 = XWu[(size_t)m1.x * 64 + lane];
            unsigned u2 = XWu[(size_t)m2.x * 64 + lane];
            unsigned u3 = XWu[(size_t)m3.x * 64 + lane];
            float w0 = __int_as_float(m0.y), w1 = __int_as_float(m1.y);
            float w2 = __int_as_float(m2.y), w3 = __int_as_float(m3.y);
            ax += bf_lo(u0) * w0; ay += bf_hi(u0) * w0;
            bx += bf_lo(u1) * w1; by += bf_hi(u1) * w1;
            ax += bf_lo(u2) * w2; ay += bf_hi(u2) * w2;
            bx += bf_lo(u3) * w3; by += bf_hi(u3) * w3;
        }
        for (; p < end; ++p) {
            int2 m = ep[p];
            float w = __int_as_float(m.y);
            unsigned u = XWu[(size_t)m.x * 64 + lane];
            ax += bf_lo(u) * w;
            ay += bf_hi(u) * w;
        }
        ax += bx; ay += by;

        float2 b = reinterpret_cast<const float2*>(bias)[lane];
        float ox = fmaxf(ax + b.x, 0.f);
        float oy = fmaxf(ay + b.y, 0.f);
        if constexpr (BFOUT) {
            unsigned o = ((unsigned)f2bf(oy) << 16) | (unsigned)f2bf(ox);
            reinterpret_cast<unsigned*>(OUT)[(size_t)node * 64 + lane] = o;
        } else {
            reinterpret_cast<float2*>(OUT)[(size_t)node * 64 + lane] = make_float2(ox, oy);
        }
    } else {
        float di = dinv[node];
        float sl = di * di;
        float acc0 = __uint_as_float(((unsigned)XW[(size_t)node * D + lane]) << 16) * sl;
        float acc1 = 0.f;

        int p = start;
        for (; p + 8 <= end; p += 8) {
            int2 m0 = ep[p + 0]; int2 m1 = ep[p + 1];
            int2 m2 = ep[p + 2]; int2 m3 = ep[p + 3];
            int2 m4 = ep[p + 4]; int2 m5 = ep[p + 5];
            int2 m6 = ep[p + 6]; int2 m7 = ep[p + 7];
            float u0 = __uint_as_float(((unsigned)XW[(size_t)m0.x * D + lane]) << 16);
            float u1 = __uint_as_float(((unsigned)XW[(size_t)m1.x * D + lane]) << 16);
            float u2 = __uint_as_float(((unsigned)XW[(size_t)m2.x * D + lane]) << 16);
            float u3 = __uint_as_float(((unsigned)XW[(size_t)m3.x * D + lane]) << 16);
            float u4 = __uint_as_float(((unsigned)XW[(size_t)m4.x * D + lane]) << 16);
            float u5 = __uint_as_float(((unsigned)XW[(size_t)m5.x * D + lane]) << 16);
            float u6 = __uint_as_float(((unsigned)XW[(size_t)m6.x * D + lane]) << 16);
            float u7 = __uint_as_float(((unsigned)XW[(size_t)m7.x * D + lane]) << 16);
            acc0 += u0 * __int_as_float(m0.y);
            acc1 += u1 * __int_as_float(m1.y);
            acc0 += u2 * __int_as_float(m2.y);
            acc1 += u3 * __int_as_float(m3.y);
            acc0 += u4 * __int_as_float(m4.y);
            acc1 += u5 * __int_as_float(m5.y);
            acc0 += u6 * __int_as_float(m6.y);
            acc1 += u7 * __int_as_float(m7.y);
        }
        for (; p + 4 <= end; p += 4) {
            int2 m0 = ep[p + 0]; int2 m1 = ep[p + 1];
            int2 m2 = ep[p + 2]; int2 m3 = ep[p + 3];
            float u0 = __uint_as_float(((unsigned)XW[(size_t)m0.x * D + lane]) << 16);
            float u1 = __uint_as_float(((unsigned)XW[(size_t)m1.x * D + lane]) << 16);
            float u2 = __uint_as_float(((unsigned)XW[(size_t)m2.x * D + lane]) << 16);
            float u3 = __uint_as_float(((unsigned)XW[(size_t)m3.x * D + lane]) << 16);
            acc0 += u0 * __int_as_float(m0.y);
            acc1 += u1 * __int_as_float(m1.y);
            acc0 += u2 * __int_as_float(m2.y);
            acc1 += u3 * __int_as_float(m3.y);
        }
        for (; p < end; ++p) {
            int2 m = ep[p];
            acc0 += __uint_as_float(((unsigned)XW[(size_t)m.x * D + lane]) << 16) * __int_as_float(m.y);
        }
        acc0 += acc1;

        float o = fmaxf(acc0 + bias[lane], 0.f);
        reinterpret_cast<float*>(OUT)[(size_t)node * D + lane] = o;
    }
}

// ---------------- pooling: segmented reduction over sorted batch ----------------
#define POOL_CHUNK 64

__global__ __launch_bounds__(256) void pool_seg_kernel(const float* __restrict__ H,
                                                       const int* __restrict__ batch,
                                                       float* __restrict__ sums,
                                                       float* __restrict__ cnt, int n) {
    const int wave = (blockIdx.x * 256 + threadIdx.x) >> 6;
    const int lane = threadIdx.x & 63;
    int i0 = wave * POOL_CHUNK;
    if (i0 >= n) return;
    int i1 = min(i0 + POOL_CHUNK, n);

    int g = batch[i0];
    float acc = 0.0f;
    int segn = 0;
    for (int i = i0; i < i1; ++i) {
        int gi = batch[i];
        if (gi != g) {
            unsafeAtomicAdd(&sums[g * DOUTC + lane], acc);
            if (lane == 0) unsafeAtomicAdd(&cnt[g], (float)segn);
            g = gi;
            acc = 0.0f;
            segn = 0;
        }
        acc += H[(size_t)i * DOUTC + lane];
        ++segn;
    }
    unsafeAtomicAdd(&sums[g * DOUTC + lane], acc);
    if (lane == 0) unsafeAtomicAdd(&cnt[g], (float)segn);
}

__global__ void pool_finish_kernel(const float* __restrict__ sums, const float* __restrict__ cnt,
                                   float* __restrict__ out, int g_total) {
    int t = blockIdx.x * blockDim.x + threadIdx.x;
    if (t >= g_total * DOUTC) return;
    int g = t >> 6;
    out[t] = sums[t] / fmaxf(cnt[g], 1.0f);
}

// ---------------- launch ----------------

extern "C" void kernel_launch(void* const* d_in, const int* in_sizes, int n_in,
                              void* d_out, int out_size, void* d_ws, size_t ws_size,
                              hipStream_t stream) {
    const float* x    = (const float*)d_in[0];
    const int*   ei   = (const int*)d_in[1];   // [2][E], int32 per harness convention
    const int*   batch= (const int*)d_in[2];   // int32 per harness convention
    const float* W1   = (const float*)d_in[3];
    const float* b1   = (const float*)d_in[4];
    const float* W2   = (const float*)d_in[5];
    const float* b2   = (const float*)d_in[6];
    float* out = (float*)d_out;

    const int N = in_sizes[0] / DIN;
    const int E = in_sizes[1] / 2;
    const int G = out_size / DOUTC;

    const int* esrc = ei;
    const int* edst = ei + E;

    // workspace carve-out (256B aligned)
    char* ws = (char*)d_ws;
    size_t off = 0;
    auto alloc = [&](size_t bytes) -> void* {
        void* p = ws + off;
        off = (off + bytes + 255) & ~(size_t)255;
        return p;
    };
    float* dinv    = (float*)alloc((size_t)N * 4);
    int*   row_ptr = (int*)alloc((size_t)(N + 1) * 4);
    int*   deg     = (int*)alloc((size_t)N * 4);
    int*   rank    = (int*)alloc((size_t)E * 4);
    int*   blockSums = (int*)alloc(1024 * 4);
    int2*  epack   = (int2*)alloc((size_t)E * 8);                       // {src, norm}
    unsigned short* xwbf = (unsigned short*)alloc((size_t)N * DH * 2);  // XW1 / XW2 (bf16)
    unsigned short* h1bf = (unsigned short*)alloc((size_t)N * DH * 2);  // h1 (bf16)
    float* bufB    = (float*)alloc((size_t)N * DOUTC * 4);              // h2 (f32)
    float* sums    = (float*)alloc((size_t)G * DOUTC * 4 + (size_t)G * 4);
    float* cnt     = sums + G * DOUTC;

    const int B = 256;
    auto cdiv = [](long long a, long long b) { return (int)((a + b - 1) / b); };
    const int nScanBlocks = cdiv(N, 1024);
    const int nG = cdiv(N, 64);             // 64-row gemm1 tiles
    const int nS = cdiv(E, B);              // scatter blocks
    const int initM = G * DOUTC + G;

    // ---- init + standalone deg_count (full TLP for the atomic storm) ----
    init_kernel<<<cdiv(N > initM ? N : initM, B), B, 0, stream>>>(deg, sums, N, initM);
    deg_count_kernel<<<cdiv(E, B), B, 0, stream>>>(deg, edst, rank, E);

    // ---- scan ----
    scan1_kernel<<<nScanBlocks, B, 0, stream>>>(deg, row_ptr, blockSums, dinv, N);
    scan2_kernel<<<1, 64, 0, stream>>>(blockSums, nScanBlocks);
    scan3_kernel<<<cdiv(N, B), B, 0, stream>>>(row_ptr, blockSums, N, E);

    // ---- fused {gemm1 interleaved with scatter} ----
    gemm1_scatter_kernel<<<nG + nS, B, 0, stream>>>(x, W1, xwbf, N, esrc, edst, rank,
                                                    dinv, row_ptr, epack, E, nG);

    // ---- layer 1 aggregation: h1(bf16) = relu(agg(XW1) + b1) ----
    agg_relu_kernel<DH, true><<<cdiv(N, 4), B, 0, stream>>>(xwbf, epack, row_ptr, dinv, b1, h1bf, N);

    // ---- layer 2: XW2 = h1 @ W2 (bf16 in/out), then h2(f32) ----
    gemm_k128_bf16in<DOUTC><<<cdiv(N, 64), B, 0, stream>>>(h1bf, W2, xwbf, N);
    agg_relu_kernel<DOUTC, false><<<cdiv(N, 4), B, 0, stream>>>(xwbf, epack, row_ptr, dinv, b2, bufB, N);

    // ---- pool ----
    const int nPoolWaves = cdiv(N, POOL_CHUNK);
    pool_seg_kernel<<<cdiv((long long)nPoolWaves * 64, B), B, 0, stream>>>(bufB, batch, sums, cnt, N);
    pool_finish_kernel<<<cdiv(G * DOUTC, B), B, 0, stream>>>(sums, cnt, out, G);
}

// Round 16
// 320.219 us; speedup vs baseline: 1.0866x; 1.0866x over previous
//
#include <hip/hip_runtime.h>
#include <hip/hip_bf16.h>

// GCN encoder: 2x GCNConv(relu) + global mean pool.
// N=100000 nodes, E=1.6M edges, D 128->128->64, G=64 graphs.
// Round 16: r13 exact revert (best: 326us) + 2 trims:
//  - scan2 folded into scan3 (per-block serial prefix of <=98 blockSums)
//  - h2 stored bf16 (halves agg2 write + pool read)
// Fusion lesson (r11-r15): only {gemm1||deg} in r13's 1:4 interleave helps;
// all LDS/tile/pairing variants regressed.

#define DIN 128
#define DH  128
#define DOUTC 64

// bf16 helpers (RNE pack, shift unpack)
__device__ inline unsigned short f2bf(float f) {
    union { float f; unsigned u; } v; v.f = f;
    unsigned r = v.u + 0x7FFF + ((v.u >> 16) & 1);
    return (unsigned short)(r >> 16);
}
__device__ inline float bf_lo(unsigned u) { return __uint_as_float(u << 16); }
__device__ inline float bf_hi(unsigned u) { return __uint_as_float(u & 0xFFFF0000u); }
__device__ inline float bf1(unsigned short u) { return __uint_as_float(((unsigned)u) << 16); }

// ---------------- init: zero deg + zero pool sums in one launch ----------------
__global__ void init_kernel(int* __restrict__ deg, float* __restrict__ sums, int n, int m) {
    int i = blockIdx.x * blockDim.x + threadIdx.x;
    if (i < n) deg[i] = 0;
    if (i < m) sums[i] = 0.0f;
}

// ---------------- fat kernel: interleaved gemm1 / deg_count blocks ----------------
// role: bid%5==0 && bid/5<nG -> gemm block (64 rows, 32KB LDS); else deg block.
__global__ __launch_bounds__(256) void gemm1_deg_kernel(const float* __restrict__ X,
                                                        const float* __restrict__ W,
                                                        unsigned short* __restrict__ Y, int n,
                                                        const int* __restrict__ dst,
                                                        int* __restrict__ deg,
                                                        int* __restrict__ rank,
                                                        int e_total, int nG) {
    __shared__ float xs[64][128];   // 32 KB
    const int tid = threadIdx.x;
    const int bid = (int)blockIdx.x;
    const int q = bid / 5;
    const int r5 = bid % 5;
    const bool isGemm = (r5 == 0) && (q < nG);

    if (!isGemm) {
        int gBefore = (r5 == 0) ? q : q + 1;
        if (gBefore > nG) gBefore = nG;
        int degBlk = bid - gBefore;
        int i = degBlk * 256 + tid;
        if (i < e_total) rank[i] = atomicAdd(&deg[dst[i]], 1);
        return;
    }

    constexpr int COLV = 32;   // 128/4 float4 col groups
    constexpr int RS = 8;      // 256/COLV row slots
    constexpr int RPT = 8;     // 64/RS rows per thread

    const int row0 = q * 64;

    #pragma unroll
    for (int i = 0; i < 8; ++i) {
        int idx = i * 256 + tid;
        int r = idx >> 5;
        int c = idx & 31;
        int gr = row0 + r;
        float4 v = make_float4(0.f, 0.f, 0.f, 0.f);
        if (gr < n) v = reinterpret_cast<const float4*>(X)[(size_t)gr * 32 + c];
        reinterpret_cast<float4*>(&xs[0][0])[idx] = v;
    }
    __syncthreads();

    const int col = tid % COLV;
    const int rslot = tid / COLV;

    float4 acc[RPT];
    #pragma unroll
    for (int r = 0; r < RPT; ++r) acc[r] = make_float4(0.f, 0.f, 0.f, 0.f);

    #pragma unroll 4
    for (int k = 0; k < 128; ++k) {
        float4 w = reinterpret_cast<const float4*>(W)[k * COLV + col];
        #pragma unroll
        for (int r = 0; r < RPT; ++r) {
            float xv = xs[rslot + r * RS][k];
            acc[r].x += xv * w.x;
            acc[r].y += xv * w.y;
            acc[r].z += xv * w.z;
            acc[r].w += xv * w.w;
        }
    }

    #pragma unroll
    for (int r = 0; r < RPT; ++r) {
        int gr = row0 + rslot + r * RS;
        if (gr < n) {
            ushort4 st;
            st.x = f2bf(acc[r].x);
            st.y = f2bf(acc[r].y);
            st.z = f2bf(acc[r].z);
            st.w = f2bf(acc[r].w);
            reinterpret_cast<ushort4*>(Y)[(size_t)gr * COLV + col] = st;
        }
    }
}

// ---------------- prefix scan over deg -> row_ptr; also emits dinv ----------
__global__ __launch_bounds__(256) void scan1_kernel(const int* __restrict__ deg,
                                                    int* __restrict__ excl,
                                                    int* __restrict__ blockSums,
                                                    float* __restrict__ dinv, int n) {
    __shared__ int sh[256];
    const int tid = threadIdx.x;
    const int base = blockIdx.x * 1024 + tid * 4;
    int v[4];
    #pragma unroll
    for (int j = 0; j < 4; ++j) v[j] = (base + j < n) ? deg[base + j] : 0;
    #pragma unroll
    for (int j = 0; j < 4; ++j)
        if (base + j < n) dinv[base + j] = rsqrtf((float)(v[j] + 1));
    int tsum = v[0] + v[1] + v[2] + v[3];
    sh[tid] = tsum;
    __syncthreads();
    for (int off = 1; off < 256; off <<= 1) {
        int add = (tid >= off) ? sh[tid - off] : 0;
        __syncthreads();
        sh[tid] += add;
        __syncthreads();
    }
    int texcl = sh[tid] - tsum;
    int run = texcl;
    #pragma unroll
    for (int j = 0; j < 4; ++j) {
        if (base + j < n) excl[base + j] = run;
        run += v[j];
    }
    if (tid == 255) blockSums[blockIdx.x] = sh[255];
}

// scan3 (scan2 folded in): each block covers 256 node indices, all within one
// 1024-chunk (chunk = b/4); thread 0 serially sums blockSums[0..chunk-1].
__global__ __launch_bounds__(256) void scan3_kernel(int* __restrict__ row_ptr,
                                                    const int* __restrict__ blockSums,
                                                    int n, int e_total) {
    __shared__ int pref;
    const int tid = threadIdx.x;
    const int chunk = (int)blockIdx.x >> 2;      // 256-idx block -> 1024-chunk id
    if (tid == 0) {
        int run = 0;
        for (int c = 0; c < chunk; ++c) run += blockSums[c];
        pref = run;
    }
    __syncthreads();
    int i = (int)blockIdx.x * 256 + tid;
    if (i < n) row_ptr[i] += pref;
    if (i == 0) row_ptr[n] = e_total;
}

// atomic-free scatter: ep[row_ptr[dst] + rank[e]] = {src, dinv[src]*dinv[dst]}
__global__ void scatter_kernel(const int* __restrict__ src, const int* __restrict__ dst,
                               const int* __restrict__ rank, const float* __restrict__ dinv,
                               const int* __restrict__ row_ptr,
                               int2* __restrict__ ep, int e_total) {
    int e = blockIdx.x * blockDim.x + threadIdx.x;
    if (e >= e_total) return;
    int s = src[e];
    int d = dst[e];
    int r = rank[e];
    float ds = dinv[s];
    float dd = dinv[d];
    int pos = row_ptr[d] + r;
    ep[pos] = make_int2(s, __float_as_int(ds * dd));
}

// ---------------- GEMM2: Y[n][DOUT] = H1[n][128](bf16) * W[128][DOUT], bf16 out ----
template <int DOUT>
__global__ __launch_bounds__(256) void gemm_k128_bf16in(const unsigned short* __restrict__ X,
                                                        const float* __restrict__ W,
                                                        unsigned short* __restrict__ Y, int n) {
    constexpr int COLV = DOUT / 4;
    constexpr int RS = 256 / COLV;
    constexpr int RPT = 64 / RS;

    __shared__ float xs[64][128];

    const int tid = threadIdx.x;
    const int row0 = (int)blockIdx.x * 64;

    // stage 64x128 bf16 tile -> f32 LDS: 1024 uint4 (16B = 8 bf16), 4/thread
    #pragma unroll
    for (int i = 0; i < 4; ++i) {
        int idx = i * 256 + tid;     // uint4 index; 16 per row
        int r = idx >> 4;
        int c8 = idx & 15;
        uint4 v = make_uint4(0, 0, 0, 0);
        if (row0 + r < n) v = reinterpret_cast<const uint4*>(X)[(size_t)(row0 + r) * 16 + c8];
        float* dp = &xs[r][c8 * 8];
        dp[0] = bf_lo(v.x); dp[1] = bf_hi(v.x);
        dp[2] = bf_lo(v.y); dp[3] = bf_hi(v.y);
        dp[4] = bf_lo(v.z); dp[5] = bf_hi(v.z);
        dp[6] = bf_lo(v.w); dp[7] = bf_hi(v.w);
    }
    __syncthreads();

    const int col = tid % COLV;
    const int rslot = tid / COLV;

    float4 acc[RPT];
    #pragma unroll
    for (int r = 0; r < RPT; ++r) acc[r] = make_float4(0.f, 0.f, 0.f, 0.f);

    #pragma unroll 4
    for (int k = 0; k < 128; ++k) {
        float4 w = reinterpret_cast<const float4*>(W)[k * COLV + col];
        #pragma unroll
        for (int r = 0; r < RPT; ++r) {
            float xv = xs[rslot + r * RS][k];
            acc[r].x += xv * w.x;
            acc[r].y += xv * w.y;
            acc[r].z += xv * w.z;
            acc[r].w += xv * w.w;
        }
    }

    #pragma unroll
    for (int r = 0; r < RPT; ++r) {
        int gr = row0 + rslot + r * RS;
        if (gr < n) {
            ushort4 st;
            st.x = f2bf(acc[r].x);
            st.y = f2bf(acc[r].y);
            st.z = f2bf(acc[r].z);
            st.w = f2bf(acc[r].w);
            reinterpret_cast<ushort4*>(Y)[(size_t)gr * COLV + col] = st;
        }
    }
}

// ---------------- fused CSR aggregation + selfloop + bias + relu ----------------
// One wave per node; 8x unrolled edge loop over int2 {src, norm} records;
// XW bf16, f32 accumulation. BFOUT selects bf16 vs f32 output (both D).
template <int D, bool BFOUT>
__global__ __launch_bounds__(256) void agg_relu_kernel(const unsigned short* __restrict__ XW,
                                                       const int2* __restrict__ ep,
                                                       const int* __restrict__ row_ptr,
                                                       const float* __restrict__ dinv,
                                                       const float* __restrict__ bias,
                                                       void* __restrict__ OUT, int n) {
    const int tid = threadIdx.x;
    const int node = (blockIdx.x * 256 + tid) >> 6;
    const int lane = tid & 63;
    if (node >= n) return;

    const int start = row_ptr[node];
    const int end = row_ptr[node + 1];

    if constexpr (D == 128) {
        const unsigned* XWu = reinterpret_cast<const unsigned*>(XW);  // 64 uints/row
        float di = dinv[node];
        float sl = di * di;
        unsigned rv = XWu[(size_t)node * 64 + lane];
        float ax = bf_lo(rv) * sl, ay = bf_hi(rv) * sl;
        float bx = 0.f, by = 0.f;

        int p = start;
        for (; p + 8 <= end; p += 8) {
            int2 m0 = ep[p + 0]; int2 m1 = ep[p + 1];
            int2 m2 = ep[p + 2]; int2 m3 = ep[p + 3];
            int2 m4 = ep[p + 4]; int2 m5 = ep[p + 5];
            int2 m6 = ep[p + 6]; int2 m7 = ep[p + 7];
            unsigned u0 = XWu[(size_t)m0.x * 64 + lane];
            unsigned u1 = XWu[(size_t)m1.x * 64 + lane];
            unsigned u2 = XWu[(size_t)m2.x * 64 + lane];
            unsigned u3 = XWu[(size_t)m3.x * 64 + lane];
            unsigned u4 = XWu[(size_t)m4.x * 64 + lane];
            unsigned u5 = XWu[(size_t)m5.x * 64 + lane];
            unsigned u6 = XWu[(size_t)m6.x * 64 + lane];
            unsigned u7 = XWu[(size_t)m7.x * 64 + lane];
            float w0 = __int_as_float(m0.y), w1 = __int_as_float(m1.y);
            float w2 = __int_as_float(m2.y), w3 = __int_as_float(m3.y);
            float w4 = __int_as_float(m4.y), w5 = __int_as_float(m5.y);
            float w6 = __int_as_float(m6.y), w7 = __int_as_float(m7.y);
            ax += bf_lo(u0) * w0; ay += bf_hi(u0) * w0;
            bx += bf_lo(u1) * w1; by += bf_hi(u1) * w1;
            ax += bf_lo(u2) * w2; ay += bf_hi(u2) * w2;
            bx += bf_lo(u3) * w3; by += bf_hi(u3) * w3;
            ax += bf_lo(u4) * w4; ay += bf_hi(u4) * w4;
            bx += bf_lo(u5) * w5; by += bf_hi(u5) * w5;
            ax += bf_lo(u6) * w6; ay += bf_hi(u6) * w6;
            bx += bf_lo(u7) * w7; by += bf_hi(u7) * w7;
        }
        for (; p + 4 <= end; p += 4) {
            int2 m0 = ep[p + 0]; int2 m1 = ep[p + 1];
            int2 m2 = ep[p + 2]; int2 m3 = ep[p + 3];
            unsigned u0 = XWu[(size_t)m0.x * 64 + lane];
            unsigned u1 = XWu[(size_t)m1.x * 64 + lane];
            unsigned u2 = XWu[(size_t)m2.x * 64 + lane];
            unsigned u3 = XWu[(size_t)m3.x * 64 + lane];
            float w0 = __int_as_float(m0.y), w1 = __int_as_float(m1.y);
            float w2 = __int_as_float(m2.y), w3 = __int_as_float(m3.y);
            ax += bf_lo(u0) * w0; ay += bf_hi(u0) * w0;
            bx += bf_lo(u1) * w1; by += bf_hi(u1) * w1;
            ax += bf_lo(u2) * w2; ay += bf_hi(u2) * w2;
            bx += bf_lo(u3) * w3; by += bf_hi(u3) * w3;
        }
        for (; p < end; ++p) {
            int2 m = ep[p];
            float w = __int_as_float(m.y);
            unsigned u = XWu[(size_t)m.x * 64 + lane];
            ax += bf_lo(u) * w;
            ay += bf_hi(u) * w;
        }
        ax += bx; ay += by;

        float2 b = reinterpret_cast<const float2*>(bias)[lane];
        float ox = fmaxf(ax + b.x, 0.f);
        float oy = fmaxf(ay + b.y, 0.f);
        if constexpr (BFOUT) {
            unsigned o = ((unsigned)f2bf(oy) << 16) | (unsigned)f2bf(ox);
            reinterpret_cast<unsigned*>(OUT)[(size_t)node * 64 + lane] = o;
        } else {
            reinterpret_cast<float2*>(OUT)[(size_t)node * 64 + lane] = make_float2(ox, oy);
        }
    } else {
        float di = dinv[node];
        float sl = di * di;
        float acc0 = bf1(XW[(size_t)node * D + lane]) * sl;
        float acc1 = 0.f;

        int p = start;
        for (; p + 8 <= end; p += 8) {
            int2 m0 = ep[p + 0]; int2 m1 = ep[p + 1];
            int2 m2 = ep[p + 2]; int2 m3 = ep[p + 3];
            int2 m4 = ep[p + 4]; int2 m5 = ep[p + 5];
            int2 m6 = ep[p + 6]; int2 m7 = ep[p + 7];
            float u0 = bf1(XW[(size_t)m0.x * D + lane]);
            float u1 = bf1(XW[(size_t)m1.x * D + lane]);
            float u2 = bf1(XW[(size_t)m2.x * D + lane]);
            float u3 = bf1(XW[(size_t)m3.x * D + lane]);
            float u4 = bf1(XW[(size_t)m4.x * D + lane]);
            float u5 = bf1(XW[(size_t)m5.x * D + lane]);
            float u6 = bf1(XW[(size_t)m6.x * D + lane]);
            float u7 = bf1(XW[(size_t)m7.x * D + lane]);
            acc0 += u0 * __int_as_float(m0.y);
            acc1 += u1 * __int_as_float(m1.y);
            acc0 += u2 * __int_as_float(m2.y);
            acc1 += u3 * __int_as_float(m3.y);
            acc0 += u4 * __int_as_float(m4.y);
            acc1 += u5 * __int_as_float(m5.y);
            acc0 += u6 * __int_as_float(m6.y);
            acc1 += u7 * __int_as_float(m7.y);
        }
        for (; p + 4 <= end; p += 4) {
            int2 m0 = ep[p + 0]; int2 m1 = ep[p + 1];
            int2 m2 = ep[p + 2]; int2 m3 = ep[p + 3];
            float u0 = bf1(XW[(size_t)m0.x * D + lane]);
            float u1 = bf1(XW[(size_t)m1.x * D + lane]);
            float u2 = bf1(XW[(size_t)m2.x * D + lane]);
            float u3 = bf1(XW[(size_t)m3.x * D + lane]);
            acc0 += u0 * __int_as_float(m0.y);
            acc1 += u1 * __int_as_float(m1.y);
            acc0 += u2 * __int_as_float(m2.y);
            acc1 += u3 * __int_as_float(m3.y);
        }
        for (; p < end; ++p) {
            int2 m = ep[p];
            acc0 += bf1(XW[(size_t)m.x * D + lane]) * __int_as_float(m.y);
        }
        acc0 += acc1;

        float o = fmaxf(acc0 + bias[lane], 0.f);
        if constexpr (BFOUT) {
            reinterpret_cast<unsigned short*>(OUT)[(size_t)node * D + lane] = f2bf(o);
        } else {
            reinterpret_cast<float*>(OUT)[(size_t)node * D + lane] = o;
        }
    }
}

// ---------------- pooling: segmented reduction over sorted batch (bf16 in) ----
#define POOL_CHUNK 64

__global__ __launch_bounds__(256) void pool_seg_kernel(const unsigned short* __restrict__ H,
                                                       const int* __restrict__ batch,
                                                       float* __restrict__ sums,
                                                       float* __restrict__ cnt, int n) {
    const int wave = (blockIdx.x * 256 + threadIdx.x) >> 6;
    const int lane = threadIdx.x & 63;
    int i0 = wave * POOL_CHUNK;
    if (i0 >= n) return;
    int i1 = min(i0 + POOL_CHUNK, n);

    int g = batch[i0];
    float acc = 0.0f;
    int segn = 0;
    for (int i = i0; i < i1; ++i) {
        int gi = batch[i];
        if (gi != g) {
            unsafeAtomicAdd(&sums[g * DOUTC + lane], acc);
            if (lane == 0) unsafeAtomicAdd(&cnt[g], (float)segn);
            g = gi;
            acc = 0.0f;
            segn = 0;
        }
        acc += bf1(H[(size_t)i * DOUTC + lane]);
        ++segn;
    }
    unsafeAtomicAdd(&sums[g * DOUTC + lane], acc);
    if (lane == 0) unsafeAtomicAdd(&cnt[g], (float)segn);
}

__global__ void pool_finish_kernel(const float* __restrict__ sums, const float* __restrict__ cnt,
                                   float* __restrict__ out, int g_total) {
    int t = blockIdx.x * blockDim.x + threadIdx.x;
    if (t >= g_total * DOUTC) return;
    int g = t >> 6;
    out[t] = sums[t] / fmaxf(cnt[g], 1.0f);
}

// ---------------- launch ----------------

extern "C" void kernel_launch(void* const* d_in, const int* in_sizes, int n_in,
                              void* d_out, int out_size, void* d_ws, size_t ws_size,
                              hipStream_t stream) {
    const float* x    = (const float*)d_in[0];
    const int*   ei   = (const int*)d_in[1];   // [2][E], int32 per harness convention
    const int*   batch= (const int*)d_in[2];   // int32 per harness convention
    const float* W1   = (const float*)d_in[3];
    const float* b1   = (const float*)d_in[4];
    const float* W2   = (const float*)d_in[5];
    const float* b2   = (const float*)d_in[6];
    float* out = (float*)d_out;

    const int N = in_sizes[0] / DIN;
    const int E = in_sizes[1] / 2;
    const int G = out_size / DOUTC;

    const int* esrc = ei;
    const int* edst = ei + E;

    // workspace carve-out (256B aligned)
    char* ws = (char*)d_ws;
    size_t off = 0;
    auto alloc = [&](size_t bytes) -> void* {
        void* p = ws + off;
        off = (off + bytes + 255) & ~(size_t)255;
        return p;
    };
    float* dinv    = (float*)alloc((size_t)N * 4);
    int*   row_ptr = (int*)alloc((size_t)(N + 1) * 4);
    int*   deg     = (int*)alloc((size_t)N * 4);
    int*   rank    = (int*)alloc((size_t)E * 4);
    int*   blockSums = (int*)alloc(1024 * 4);
    int2*  epack   = (int2*)alloc((size_t)E * 8);                       // {src, norm}
    unsigned short* xwbf = (unsigned short*)alloc((size_t)N * DH * 2);  // XW1 / XW2 (bf16)
    unsigned short* h1bf = (unsigned short*)alloc((size_t)N * DH * 2);  // h1 (bf16)
    unsigned short* h2bf = (unsigned short*)alloc((size_t)N * DOUTC * 2); // h2 (bf16)
    float* sums    = (float*)alloc((size_t)G * DOUTC * 4 + (size_t)G * 4);
    float* cnt     = sums + G * DOUTC;

    const int B = 256;
    auto cdiv = [](long long a, long long b) { return (int)((a + b - 1) / b); };
    const int nScanBlocks = cdiv(N, 1024);
    const int nG = cdiv(N, 64);             // 64-row gemm1 tiles
    const int nD = cdiv(E, B);
    const int initM = G * DOUTC + G;

    // ---- init + fused {gemm1 interleaved with deg_count} ----
    init_kernel<<<cdiv(N > initM ? N : initM, B), B, 0, stream>>>(deg, sums, N, initM);
    gemm1_deg_kernel<<<nG + nD, B, 0, stream>>>(x, W1, xwbf, N, edst, deg, rank, E, nG);

    // ---- scan (scan2 folded into scan3) + atomic-free scatter ----
    scan1_kernel<<<nScanBlocks, B, 0, stream>>>(deg, row_ptr, blockSums, dinv, N);
    scan3_kernel<<<cdiv(N, B), B, 0, stream>>>(row_ptr, blockSums, N, E);
    scatter_kernel<<<cdiv(E, B), B, 0, stream>>>(esrc, edst, rank, dinv, row_ptr, epack, E);

    // ---- layer 1 aggregation: h1(bf16) = relu(agg(XW1) + b1) ----
    agg_relu_kernel<DH, true><<<cdiv(N, 4), B, 0, stream>>>(xwbf, epack, row_ptr, dinv, b1, h1bf, N);

    // ---- layer 2: XW2 = h1 @ W2 (bf16 in/out), then h2(bf16) ----
    gemm_k128_bf16in<DOUTC><<<cdiv(N, 64), B, 0, stream>>>(h1bf, W2, xwbf, N);
    agg_relu_kernel<DOUTC, true><<<cdiv(N, 4), B, 0, stream>>>(xwbf, epack, row_ptr, dinv, b2, h2bf, N);

    // ---- pool ----
    const int nPoolWaves = cdiv(N, POOL_CHUNK);
    pool_seg_kernel<<<cdiv((long long)nPoolWaves * 64, B), B, 0, stream>>>(h2bf, batch, sums, cnt, N);
    pool_finish_kernel<<<cdiv(G * DOUTC, B), B, 0, stream>>>(sums, cnt, out, G);
}